// Round 2
// baseline (81.290 us; speedup 1.0000x reference)
//
#include <hip/hip_runtime.h>

// InnerProduct: x (B=4096, F=39, D=64) fp32 -> out (B, 741) fp32
// out[b, p(i,j)] = dot(x[b,i,:], x[b,j,:]) for i<j.
//
// R1: scattered 4B global stores -> 414 MB writes. Fix: LDS-staged coalesced copy.
// R2: forced unroll + launch_bounds(256,3) -> spill -> 1 GB scratch. Fix: lean loop.
// R4: bf16 MFMA Gram, 12 mfma/wave -> kernel ~21 us; harness poison ~58 us dominates.
// R5: fragments straight from global (no input LDS round-trip).
// R6: split each batch across 2 waves to break the occupancy/serialization
//     ceiling. 4096 waves (=16/CU, half of max) -> 8192 waves; per-wave regs drop
//     (3 accs, <=3 frags) so launch_bounds(256,8) targets 8 waves/SIMD. Wave A owns
//     tiles (0,0),(0,1),(0,2) -> output rows i<16 -> p in [0,488); wave B owns
//     (1,1),(1,2),(2,2) -> p in [488,741). Contiguous disjoint p-ranges => each wave
//     scatters+copies its own LDS region: NO __syncthreads at all. Tile-specialized
//     scatter guards (cndmask to pad slot, incremental triangular base).
//     Duplicate f1/f2 loads between sibling waves merge in L1 (same CU) -> HBM same.
// R7: identical resubmit — R6 bench never ran (GPU acquisition timeout).
//
// Fragment facts (guide-verified): A[m=lane&15][k=(lane>>4)*8+j], B same layout
// (Gram, X.X^T). C/D: col=lane&15, row=(lane>>4)*4+reg.

typedef __bf16 bf16x8 __attribute__((ext_vector_type(8)));
typedef float  f32x4  __attribute__((ext_vector_type(4)));

constexpr int NFIELD    = 39;
constexpr int DIM       = 64;
constexpr int NPAIR     = 741;   // C(39,2)
constexpr int BPB       = 2;     // batches per block (2 waves each)
constexpr int ROWSTRIDE = 768;   // padded LDS row (floats); [741..767] = pad/dummy
constexpr int PSPLIT    = 488;   // p(16,17): first pair with i>=16

__global__ __launch_bounds__(256, 8)
void ip_kernel(const float* __restrict__ x, float* __restrict__ out, int batches) {
    __shared__ __align__(16) float lds_out[BPB][ROWSTRIDE];   // 6144 B

    const int tid  = threadIdx.x;
    const int wv   = tid >> 6;
    const int lane = tid & 63;
    const int role = wv & 1;                 // 0: row-tile 0; 1: row-tiles 1,2
    const int b0   = blockIdx.x * BPB;
    const int batch = b0 + (wv >> 1);
    if (batch >= batches) return;            // no barriers anywhere: safe

    const int m = lane & 15;                 // fragment row-within-tile / out col
    const int q = lane >> 4;                 // quad -> k sub-chunk + out row group
    const float* xb = x + (size_t)batch * (NFIELD * DIM);
    float* ldsrow = &lds_out[wv >> 1][0];

    // ---- fragment load straight from global: fr[s] = X[16t+m][32s+8q ..+8] ----
    auto loadfrag = [&](int t, bf16x8 fr[2]) {
        int row = 16 * t + m;
        if (row >= NFIELD) row = NFIELD - 1;   // dup data only feeds discarded outs
        #pragma unroll
        for (int s = 0; s < 2; ++s) {
            const float* p = xb + row * DIM + 32 * s + 8 * q;
            f32x4 u = *(const f32x4*)p;
            f32x4 v = *(const f32x4*)(p + 4);
            bf16x8 w;
            w[0] = (__bf16)u[0]; w[1] = (__bf16)u[1];
            w[2] = (__bf16)u[2]; w[3] = (__bf16)u[3];
            w[4] = (__bf16)v[0]; w[5] = (__bf16)v[1];
            w[6] = (__bf16)v[2]; w[7] = (__bf16)v[3];
            fr[s] = w;
        }
    };

    // ---- scatter one 16x16 tile's 4 accum entries into own LDS range ----
    // diag: need i<j;  jclip: need j<NFIELD (i.e. m<7). Invalid -> pad slot.
    auto scatter = [&](const f32x4& a, int ti, int tj, bool diag, bool jclip) {
        int i = 16 * ti + 4 * q;                     // C/D row for r=0
        const int j = 16 * tj + m;                   // C/D col
        int base = 37 * i - (i * (i - 1)) / 2 - 1;   // p(i,j) = base + j
        #pragma unroll
        for (int r = 0; r < 4; ++r) {
            bool ok = (!diag || (i < j)) && (!jclip || (j < NFIELD));
            int p = ok ? (base + j) : (744 + (role << 3) + r);
            ldsrow[p] = a[r];
            base += 37 - i; ++i;
        }
    };

    bf16x8 f1[2], f2[2];
    loadfrag(1, f1);
    loadfrag(2, f2);

    f32x4 acc0 = {0.f,0.f,0.f,0.f}, acc1 = acc0, acc2 = acc0;

    if (role == 0) {
        bf16x8 f0[2];
        loadfrag(0, f0);
        #pragma unroll
        for (int s = 0; s < 2; ++s) {
            acc0 = __builtin_amdgcn_mfma_f32_16x16x32_bf16(f0[s], f0[s], acc0, 0, 0, 0);
            acc1 = __builtin_amdgcn_mfma_f32_16x16x32_bf16(f0[s], f1[s], acc1, 0, 0, 0);
            acc2 = __builtin_amdgcn_mfma_f32_16x16x32_bf16(f0[s], f2[s], acc2, 0, 0, 0);
        }
        scatter(acc0, 0, 0, true,  false);
        scatter(acc1, 0, 1, false, false);   // always valid
        scatter(acc2, 0, 2, false, true);
    } else {
        #pragma unroll
        for (int s = 0; s < 2; ++s) {
            acc0 = __builtin_amdgcn_mfma_f32_16x16x32_bf16(f1[s], f1[s], acc0, 0, 0, 0);
            acc1 = __builtin_amdgcn_mfma_f32_16x16x32_bf16(f1[s], f2[s], acc1, 0, 0, 0);
            acc2 = __builtin_amdgcn_mfma_f32_16x16x32_bf16(f2[s], f2[s], acc2, 0, 0, 0);
        }
        scatter(acc0, 1, 1, true,  false);
        scatter(acc1, 1, 2, false, true);
        scatter(acc2, 2, 2, true,  true);
    }

    // wave's own ds_writes must land before its ds_reads (cross-lane, no barrier)
    asm volatile("s_waitcnt lgkmcnt(0)" ::: "memory");

    // ---- coalesced copy of this wave's own contiguous p-range ----
    float* dst = out + (size_t)batch * NPAIR;
    const int lo = role ? PSPLIT : 0;
    const int hi = role ? NPAIR  : PSPLIT;
    for (int i = lo + lane; i < hi; i += 64) dst[i] = ldsrow[i];
}

extern "C" void kernel_launch(void* const* d_in, const int* in_sizes, int n_in,
                              void* d_out, int out_size, void* d_ws, size_t ws_size,
                              hipStream_t stream) {
    const float* x = (const float*)d_in[0];
    float* out     = (float*)d_out;
    const int batches = in_sizes[0] / (NFIELD * DIM);   // 4096
    const int blocks  = (batches + BPB - 1) / BPB;      // 2048
    ip_kernel<<<blocks, 256, 0, stream>>>(x, out, batches);
}

// Round 3
// 80.647 us; speedup vs baseline: 1.0080x; 1.0080x over previous
//
#include <hip/hip_runtime.h>

// InnerProduct: x (B=4096, F=39, D=64) fp32 -> out (B, 741) fp32
// out[b, p(i,j)] = dot(x[b,i,:], x[b,j,:]) for i<j.
//
// R1: scattered 4B global stores -> 414 MB writes. Fix: LDS-staged coalesced copy.
// R2: forced unroll + launch_bounds(256,3) -> spill -> 1 GB scratch. Fix: lean loop.
// R4: bf16 MFMA Gram, 12 mfma/wave -> kernel ~21 us; harness poison ~58 us dominates.
// R5: fragments straight from global (no input LDS round-trip).
// R6: role-split (2 waves/batch), no barrier, per-wave dword copy -> NEUTRAL (81.3
//     vs 79.6, within fill noise). Lesson: occupancy was never the limiter — the
//     whole grid is co-resident from t=0 either way.
// R8 (this): keep role-split compute (short chain: <=3 frags, 3 accs/wave) but
//     restore the R5-style block-wide ALIGNED float4 copy: 512-thr block = 4
//     batches x 2 roles; LDS rows packed contiguously (stride 741) so the block's
//     output region is one dense 741-float4 span (dest offset blockIdx*11856 B,
//     16B-aligned). Copy = 1 unguarded + 1 guarded float4 store per thread vs
//     R6's 12 dword iterations/wave. One __syncthreads (replaces inline lgkmcnt).
//     Discriminating experiment: if bench is again insensitive, the harness floor
//     is proven and we're done.
//
// Fragment facts (guide-verified): A[m=lane&15][k=(lane>>4)*8+j], B same layout
// (Gram, X.X^T). C/D: col=lane&15, row=(lane>>4)*4+reg.

typedef __bf16 bf16x8 __attribute__((ext_vector_type(8)));
typedef float  f32x4  __attribute__((ext_vector_type(4)));

constexpr int NFIELD = 39;
constexpr int DIM    = 64;
constexpr int NPAIR  = 741;   // C(39,2)
constexpr int BPB    = 4;     // batches per block (2 waves each -> 512 threads)
constexpr int PSPLIT = 488;   // p(16,17): first pair with i>=16 (doc only)

__global__ __launch_bounds__(512)
void ip_kernel(const float* __restrict__ x, float* __restrict__ out, int batches) {
    // 4 batch rows packed at stride NPAIR (so block output is one dense span),
    // + 16-float pad landing zone for discarded scatter entries.
    __shared__ __align__(16) float lds_out[BPB * NPAIR + 16];   // 11920 B

    const int tid  = threadIdx.x;
    const int wv   = tid >> 6;               // 0..7
    const int lane = tid & 63;
    const int role = wv & 1;                 // 0: row-tile 0; 1: row-tiles 1,2
    const int lb   = wv >> 1;                // local batch 0..3
    const int b0   = blockIdx.x * BPB;
    const int batch = b0 + lb;

    if (batch < batches) {
        const int m = lane & 15;             // fragment row-within-tile / out col
        const int q = lane >> 4;             // quad -> k sub-chunk + out row group
        const float* xb = x + (size_t)batch * (NFIELD * DIM);
        float* ldsrow = &lds_out[lb * NPAIR];

        // ---- fragment load straight from global: fr[s] = X[16t+m][32s+8q ..+8]
        auto loadfrag = [&](int t, bf16x8 fr[2]) {
            int row = 16 * t + m;
            if (row >= NFIELD) row = NFIELD - 1;   // dup data -> discarded outs only
            #pragma unroll
            for (int s = 0; s < 2; ++s) {
                const float* p = xb + row * DIM + 32 * s + 8 * q;
                f32x4 u = *(const f32x4*)p;
                f32x4 v = *(const f32x4*)(p + 4);
                bf16x8 w;
                w[0] = (__bf16)u[0]; w[1] = (__bf16)u[1];
                w[2] = (__bf16)u[2]; w[3] = (__bf16)u[3];
                w[4] = (__bf16)v[0]; w[5] = (__bf16)v[1];
                w[6] = (__bf16)v[2]; w[7] = (__bf16)v[3];
                fr[s] = w;
            }
        };

        // ---- scatter one 16x16 tile's 4 accum entries into this batch's LDS row.
        // diag: need i<j;  jclip: need j<NFIELD (m<7). Invalid -> shared pad slot
        // (concurrent dword writes to the pad are benign; never read).
        auto scatter = [&](const f32x4& a, int ti, int tj, bool diag, bool jclip) {
            int i = 16 * ti + 4 * q;                     // C/D row for r=0
            const int j = 16 * tj + m;                   // C/D col
            int base = 37 * i - (i * (i - 1)) / 2 - 1;   // p(i,j) = base + j
            #pragma unroll
            for (int r = 0; r < 4; ++r) {
                bool ok = (!diag || (i < j)) && (!jclip || (j < NFIELD));
                float* dst = ok ? (ldsrow + base + j)
                               : (&lds_out[BPB * NPAIR] + ((lane + r) & 15));
                *dst = a[r];
                base += 37 - i; ++i;
            }
        };

        bf16x8 f1[2], f2[2];
        loadfrag(1, f1);
        loadfrag(2, f2);

        f32x4 acc0 = {0.f,0.f,0.f,0.f}, acc1 = acc0, acc2 = acc0;

        if (role == 0) {
            bf16x8 f0[2];
            loadfrag(0, f0);
            #pragma unroll
            for (int s = 0; s < 2; ++s) {
                acc0 = __builtin_amdgcn_mfma_f32_16x16x32_bf16(f0[s], f0[s], acc0, 0, 0, 0);
                acc1 = __builtin_amdgcn_mfma_f32_16x16x32_bf16(f0[s], f1[s], acc1, 0, 0, 0);
                acc2 = __builtin_amdgcn_mfma_f32_16x16x32_bf16(f0[s], f2[s], acc2, 0, 0, 0);
            }
            scatter(acc0, 0, 0, true,  false);
            scatter(acc1, 0, 1, false, false);   // always valid
            scatter(acc2, 0, 2, false, true);
        } else {
            #pragma unroll
            for (int s = 0; s < 2; ++s) {
                acc0 = __builtin_amdgcn_mfma_f32_16x16x32_bf16(f1[s], f1[s], acc0, 0, 0, 0);
                acc1 = __builtin_amdgcn_mfma_f32_16x16x32_bf16(f1[s], f2[s], acc1, 0, 0, 0);
                acc2 = __builtin_amdgcn_mfma_f32_16x16x32_bf16(f2[s], f2[s], acc2, 0, 0, 0);
            }
            scatter(acc0, 1, 1, true,  false);
            scatter(acc1, 1, 2, false, true);
            scatter(acc2, 2, 2, true,  true);
        }
    }
    __syncthreads();

    // ---- block-wide coalesced copy: 4 batches x 741 floats = 741 float4 ----
    const int nb_here = (batches - b0) < BPB ? (batches - b0) : BPB;
    float* dst = out + (size_t)b0 * NPAIR;               // blockIdx*11856 B, 16B-aligned
    if (nb_here == BPB) {
        const float4* s4 = (const float4*)lds_out;
        float4* d4 = (float4*)dst;
        d4[tid] = s4[tid];                               // tid < 512 <= 740: unguarded
        const int i2 = tid + 512;
        if (i2 < (BPB * NPAIR) / 4) d4[i2] = s4[i2];     // 741 float4 total
    } else {
        const int nfl = nb_here * NPAIR;
        for (int i = tid; i < nfl; i += 512) dst[i] = lds_out[i];
    }
}

extern "C" void kernel_launch(void* const* d_in, const int* in_sizes, int n_in,
                              void* d_out, int out_size, void* d_ws, size_t ws_size,
                              hipStream_t stream) {
    const float* x = (const float*)d_in[0];
    float* out     = (float*)d_out;
    const int batches = in_sizes[0] / (NFIELD * DIM);   // 4096
    const int blocks  = (batches + BPB - 1) / BPB;      // 1024
    ip_kernel<<<blocks, 512, 0, stream>>>(x, out, batches);
}